// Round 4
// baseline (123.048 us; speedup 1.0000x reference)
//
#include <hip/hip_runtime.h>
#include <math.h>

// knnLoss: B=4, N=8192, k=3. Brute-force 3-NN, LDS tiles,
// inline-asm v_pk_fma_f32 dual-fp32 distance, scalar sorted-triple select.
#define BATCH 4
#define NPTS 8192
#define TILE 512            // targets per block tile
#define TSPLIT 16           // NPTS / TILE
#define SRC_PER_BLOCK 512   // 256 threads x 2 sources
#define SRC_CHUNKS 16       // NPTS / SRC_PER_BLOCK
#define NSRC_TOT (BATCH * NPTS)  // 32768

typedef __attribute__((ext_vector_type(2))) float f2;
typedef __attribute__((ext_vector_type(4))) float f4;

// Guaranteed packed dual-FP32 FMA (compiler refuses to emit it from vector ops).
__device__ __forceinline__ f2 pk_fma(f2 a, f2 b, f2 c) {
    f2 d;
    asm("v_pk_fma_f32 %0, %1, %2, %3" : "=v"(d) : "v"(a), "v"(b), "v"(c));
    return d;
}

// Branchless insert into sorted ascending triple; 4 ops via med3.
__device__ __forceinline__ void insert3(float d, float& a0, float& a1, float& a2) {
    float h = fmaxf(a1, d);
    float m = __builtin_amdgcn_fmed3f(a0, a1, d);
    a2 = fminf(a2, h);
    a1 = m;
    a0 = fminf(a0, d);
}

// Merge two sorted triples -> sorted 3 smallest of union. 6 ops.
__device__ __forceinline__ void merge33(float a0, float a1, float a2,
                                        float& b0, float& b1, float& b2) {
    float s0 = fminf(a0, b0);
    float h  = fmaxf(a0, b0);
    float m  = fminf(a1, b1);
    float mm = fminf(a2, b2);
    b1 = fminf(h, m);
    b2 = __builtin_amdgcn_fmed3f(h, m, mm);
    b0 = s0;
}

__global__ __launch_bounds__(256) void knn_partial(const float* __restrict__ src,
                                                   const float* __restrict__ tgt,
                                                   float* __restrict__ part,
                                                   float* __restrict__ hdr) {
    // Entry e (targets 2e,2e+1): ts[2e]={x0,x1,y0,y1}, ts[2e+1]={z0,z1,w0,w1},
    // w = |t|^2 / 2 (sentinel 1e38 for invalid targets).
    __shared__ f4 ts[TILE / 2 * 2];
    const int tid = threadIdx.x;
    const int sc = blockIdx.x, tc = blockIdx.y, b = blockIdx.z;

    // Zero the 64-byte reduction header (acc/cnt/ticket) once.
    if (sc == 0 && tc == 0 && b == 0 && tid < 16) hdr[tid] = 0.0f;

    {
        const float* tb = tgt + ((size_t)b * NPTS + (size_t)tc * TILE + 2 * tid) * 3;
        float x0 = tb[0], y0 = tb[1], z0 = tb[2];
        float x1 = tb[3], y1 = tb[4], z1 = tb[5];
        float w0 = 0.5f * (x0 * x0 + y0 * y0 + z0 * z0);
        float w1 = 0.5f * (x1 * x1 + y1 * y1 + z1 * z1);
        if (!(x0 != 0.f || y0 != 0.f || z0 != 0.f)) w0 = 1.0e38f;
        if (!(x1 != 0.f || y1 != 0.f || z1 != 0.f)) w1 = 1.0e38f;
        ts[2 * tid + 0] = (f4){x0, x1, y0, y1};
        ts[2 * tid + 1] = (f4){z0, z1, w0, w1};
    }
    __syncthreads();

    // 2 sources per thread; ns = -s duplicated in both packed halves.
    f2 nx[2], ny[2], nz[2];
    #pragma unroll
    for (int s = 0; s < 2; ++s) {
        int i = sc * SRC_PER_BLOCK + tid + 256 * s;
        const float* sp = src + ((size_t)b * NPTS + i) * 3;
        float ax = sp[0], ay = sp[1], az = sp[2];
        nx[s] = (f2){-ax, -ax};
        ny[s] = (f2){-ay, -ay};
        nz[s] = (f2){-az, -az};
    }

    // 4 independent chains: [source][even/odd target], v-domain values.
    float c0[2][2], c1[2][2], c2[2][2];
    #pragma unroll
    for (int s = 0; s < 2; ++s)
        for (int h = 0; h < 2; ++h) { c0[s][h] = c1[s][h] = c2[s][h] = 3e38f; }

    #pragma unroll 8
    for (int e = 0; e < TILE / 2; ++e) {
        f4 p = ts[2 * e + 0];   // ds_read_b128, wave-broadcast (conflict-free)
        f4 q = ts[2 * e + 1];
        f2 xs = __builtin_shufflevector(p, p, 0, 1);  // subregister, no instr
        f2 ys = __builtin_shufflevector(p, p, 2, 3);
        f2 zs = __builtin_shufflevector(q, q, 0, 1);
        f2 wh = __builtin_shufflevector(q, q, 2, 3);
        #pragma unroll
        for (int s = 0; s < 2; ++s) {
            f2 v = pk_fma(xs, nx[s], wh);   // v = t^2/2 - s.t  (2 pairs/instr)
            v = pk_fma(ys, ny[s], v);
            v = pk_fma(zs, nz[s], v);
            insert3(v.x, c0[s][0], c1[s][0], c2[s][0]);
            insert3(v.y, c0[s][1], c1[s][1], c2[s][1]);
        }
    }

    // Merge odd chain into even, write sorted v-triple (coalesced).
    #pragma unroll
    for (int s = 0; s < 2; ++s) {
        merge33(c0[s][1], c1[s][1], c2[s][1], c0[s][0], c1[s][0], c2[s][0]);
        size_t flat = (size_t)b * NPTS + sc * SRC_PER_BLOCK + tid + 256 * s;
        part[((size_t)tc * 3 + 0) * NSRC_TOT + flat] = c0[s][0];
        part[((size_t)tc * 3 + 1) * NSRC_TOT + flat] = c1[s][0];
        part[((size_t)tc * 3 + 2) * NSRC_TOT + flat] = c2[s][0];
    }
}

__global__ __launch_bounds__(128) void knn_merge(const float* __restrict__ src,
                                                 const float* __restrict__ part,
                                                 float* __restrict__ acc,
                                                 float* __restrict__ cnt,
                                                 unsigned* __restrict__ ticket,
                                                 float* __restrict__ out) {
    const int gid = blockIdx.x * 128 + threadIdx.x;  // 0 .. NSRC_TOT-1
    const int b = gid >> 13;                         // uniform per block

    // 48 v-values -> 4 independent sub-triples (ILP), then merge tree.
    float t0[4], t1[4], t2[4];
    #pragma unroll
    for (int c = 0; c < 4; ++c) { t0[c] = t1[c] = t2[c] = 3e38f; }
    #pragma unroll
    for (int q = 0; q < TSPLIT * 3; ++q)
        insert3(part[(size_t)q * NSRC_TOT + gid], t0[q & 3], t1[q & 3], t2[q & 3]);
    merge33(t0[1], t1[1], t2[1], t0[0], t1[0], t2[0]);
    merge33(t0[3], t1[3], t2[3], t0[2], t1[2], t2[2]);
    merge33(t0[2], t1[2], t2[2], t0[0], t1[0], t2[0]);

    float sx = src[(size_t)gid * 3 + 0];
    float sy = src[(size_t)gid * 3 + 1];
    float sz = src[(size_t)gid * 3 + 2];
    float s2 = sx * sx + sy * sy + sz * sz;
    bool valid = (sx != 0.f) || (sy != 0.f) || (sz != 0.f);
    // Reconstruct d^2 = 2v + s^2, clamp, sqrt.
    float d0 = sqrtf(fmaxf(fmaf(2.f, t0[0], s2), 0.f));
    float d1 = sqrtf(fmaxf(fmaf(2.f, t1[0], s2), 0.f));
    float d2 = sqrtf(fmaxf(fmaf(2.f, t2[0], s2), 0.f));
    float s = valid ? (d0 + d1 + d2) : 0.f;
    float c = valid ? 1.f : 0.f;

    for (int off = 32; off >= 1; off >>= 1) {
        s += __shfl_down(s, off);
        c += __shfl_down(c, off);
    }
    __shared__ float red_s[2], red_c[2];
    int wave = threadIdx.x >> 6, lane = threadIdx.x & 63;
    if (lane == 0) { red_s[wave] = s; red_c[wave] = c; }
    __syncthreads();
    if (threadIdx.x == 0) {
        atomicAdd(&acc[b], red_s[0] + red_s[1]);
        atomicAdd(&cnt[b], red_c[0] + red_c[1]);
        __threadfence();
        unsigned t = atomicAdd(ticket, 1u);
        if (t == (unsigned)(gridDim.x - 1)) {
            float loss = 0.f;
            #pragma unroll
            for (int bb = 0; bb < BATCH; ++bb) {
                float as = atomicAdd(&acc[bb], 0.f);
                float ac = atomicAdd(&cnt[bb], 0.f);
                loss += as / (ac * 3.0f);
            }
            out[0] = loss * (1.0f / BATCH);
        }
    }
}

extern "C" void kernel_launch(void* const* d_in, const int* in_sizes, int n_in,
                              void* d_out, int out_size, void* d_ws, size_t ws_size,
                              hipStream_t stream) {
    const float* src = (const float*)d_in[0];
    const float* tgt = (const float*)d_in[1];
    float* out = (float*)d_out;

    // ws: [0,16) acc[4]; [16,32) cnt[4]; [32,36) ticket; [256,...) partials (6.29 MB)
    float* hdr = (float*)d_ws;
    float* acc = hdr;
    float* cnt = hdr + 4;
    unsigned* ticket = (unsigned*)((char*)d_ws + 32);
    float* part = (float*)((char*)d_ws + 256);

    dim3 g1(SRC_CHUNKS, TSPLIT, BATCH);  // 16 x 16 x 4 = 1024 blocks
    knn_partial<<<g1, 256, 0, stream>>>(src, tgt, part, hdr);

    knn_merge<<<dim3(NSRC_TOT / 128), 128, 0, stream>>>(src, part, acc, cnt, ticket, out);
}